// Round 10
// baseline (111.926 us; speedup 1.0000x reference)
//
#include <hip/hip_runtime.h>
#include <hip/hip_bf16.h>

#define B_ 4
#define S_ 2048
#define D_ 1024
#define H_ 16
#define DH_ 64
#define QBLK 256
#define KVBLK 128
#define NT (S_ / KVBLK)
#define EPS_ 1e-12f
#define LOG2E_ 1.44269504f

typedef __attribute__((ext_vector_type(8))) short bf16x8;
typedef __attribute__((ext_vector_type(4))) float f32x4;

static __device__ __forceinline__ unsigned short f2bf(float f) {
    __hip_bfloat16 h = __float2bfloat16(f);
    return *reinterpret_cast<unsigned short*>(&h);
}

static __device__ __forceinline__ float fast_exp2(float x) {
#if __has_builtin(__builtin_amdgcn_exp2f)
    return __builtin_amdgcn_exp2f(x);
#else
    return exp2f(x);
#endif
}

// pack two f32 -> one u32 of 2 bf16 (lo in low half), RNE
static __device__ __forceinline__ unsigned int cvt_pk_bf16(float lo, float hi) {
    unsigned int r;
    asm("v_cvt_pk_bf16_f32 %0, %1, %2" : "=v"(r) : "v"(lo), "v"(hi));
    return r;
}

// K tile [row<128][64 dims] = 8 chunks of 16B per row
static __device__ __forceinline__ int swzK(int row, int chunk) {
    return (row << 6) + ((chunk ^ (row & 7)) << 3);
}
// V tile [row<64 dims][128 tokens] = 16 chunks of 16B per row
static __device__ __forceinline__ int swzV(int row, int chunk) {
    return (row << 7) + ((chunk ^ (row & 15)) << 3);
}

// k-row permutation (within 32-row blocks): label kk -> storage row, so that
// swapped-QK^T C-registers come out in PV A-fragment packing order.
// perm(8g+4nn+j) = 16nn+4g+j
static __device__ __forceinline__ int kperm(int kk) {
    return ((kk & 4) << 2) | ((kk >> 1) & 12) | (kk & 3);
}

// ---------------------------------------------------------------------------
__global__ __launch_bounds__(256) void wcast_kernel(
    const float* __restrict__ Wq, const float* __restrict__ Wk,
    const float* __restrict__ Wv, unsigned short* __restrict__ wbf)
{
    const int idx = blockIdx.x * 256 + threadIdx.x;
    const int i = idx * 4;
    const int mat = i >> 16;
    const int off = i & 65535;
    const float* src = (mat == 0) ? Wq : (mat == 1) ? Wk : Wv;
    float4 v = *reinterpret_cast<const float4*>(src + off);
    ushort4 o;
    o.x = f2bf(v.x); o.y = f2bf(v.y); o.z = f2bf(v.z); o.w = f2bf(v.w);
    *reinterpret_cast<ushort4*>(wbf + i) = o;
}

// ---------------------------------------------------------------------------
// MFMA projection (round-3 version, measured-good). Stores NORMALIZED q,k
// (q pre-scaled by temp*log2e), v^T. k rows PERMUTED (kperm) within 32-token
// blocks. q/k via direct global stores; v via LDS transpose.
// ---------------------------------------------------------------------------
__global__ __launch_bounds__(256) void proj_kernel(
    const float* __restrict__ x, const unsigned short* __restrict__ wbf,
    const float* __restrict__ bq, const float* __restrict__ bk,
    const float* __restrict__ bv, const float* __restrict__ temp,
    unsigned short* __restrict__ q_ws, unsigned short* __restrict__ k_ws,
    unsigned short* __restrict__ v_ws)
{
    __shared__ unsigned short x_lds[64][72];
    __shared__ unsigned short vt_lds[64][72];

    const int h    = blockIdx.y;
    const int tok0 = blockIdx.x * 64;
    const int b    = tok0 >> 11;
    const int s0   = tok0 & (S_ - 1);
    const int bh   = b * H_ + h;
    const int t    = threadIdx.x;
    const int wave = t >> 6, lane = t & 63, c = lane & 15, g = lane >> 4;

    {
        const int row = t >> 2, seg = t & 3;
        const float* xp = x + (size_t)(tok0 + row) * D_ + h * DH_ + seg * 16;
#pragma unroll
        for (int i = 0; i < 4; ++i) {
            float4 v = *reinterpret_cast<const float4*>(xp + i * 4);
            ushort4 o;
            o.x = f2bf(v.x); o.y = f2bf(v.y); o.z = f2bf(v.z); o.w = f2bf(v.w);
            *reinterpret_cast<ushort4*>(&x_lds[row][seg * 16 + i * 4]) = o;
        }
    }
    __syncthreads();

    bf16x8 a0 = *reinterpret_cast<const bf16x8*>(&x_lds[wave * 16 + c][g * 8]);
    bf16x8 a1 = *reinterpret_cast<const bf16x8*>(&x_lds[wave * 16 + c][32 + g * 8]);

    const float scaleq = fmaxf(temp[h], 0.01f) * LOG2E_;

#pragma unroll
    for (int mat = 0; mat < 3; ++mat) {
        const unsigned short* wb = wbf + mat * (H_ * DH_ * DH_) + h * (DH_ * DH_);
        const float* bias = ((mat == 0) ? bq : (mat == 1) ? bk : bv) + h * DH_;

        f32x4 acc[4];
#pragma unroll
        for (int m = 0; m < 4; ++m) acc[m] = (f32x4){0.f, 0.f, 0.f, 0.f};
#pragma unroll
        for (int m = 0; m < 4; ++m) {
            bf16x8 b0 = *reinterpret_cast<const bf16x8*>(wb + (m * 16 + c) * DH_ + g * 8);
            bf16x8 b1 = *reinterpret_cast<const bf16x8*>(wb + (m * 16 + c) * DH_ + 32 + g * 8);
            acc[m] = __builtin_amdgcn_mfma_f32_16x16x32_bf16(a0, b0, acc[m], 0, 0, 0);
            acc[m] = __builtin_amdgcn_mfma_f32_16x16x32_bf16(a1, b1, acc[m], 0, 0, 0);
        }
#pragma unroll
        for (int m = 0; m < 4; ++m) {
            float bm = bias[m * 16 + c];
#pragma unroll
            for (int j = 0; j < 4; ++j) acc[m][j] += bm;
        }

        if (mat < 2) {
            float rinv[4];
            const float sc = (mat == 0) ? scaleq : 1.0f;
#pragma unroll
            for (int j = 0; j < 4; ++j) {
                float p = acc[0][j] * acc[0][j] + acc[1][j] * acc[1][j] +
                          acc[2][j] * acc[2][j] + acc[3][j] * acc[3][j];
                p += __shfl_xor(p, 1); p += __shfl_xor(p, 2);
                p += __shfl_xor(p, 4); p += __shfl_xor(p, 8);
                rinv[j] = sc / fmaxf(sqrtf(p), EPS_);
            }
            unsigned short* dst = (mat == 0) ? q_ws : k_ws;
#pragma unroll
            for (int m = 0; m < 4; ++m)
#pragma unroll
                for (int j = 0; j < 4; ++j) {
                    int sl = wave * 16 + 4 * g + j;              // token within 64-tile
                    int row = (mat == 1) ? ((sl & ~31) | kperm(sl & 31)) : sl;
                    dst[((size_t)bh * S_ + s0 + row) * DH_ + m * 16 + c] =
                        f2bf(acc[m][j] * rinv[j]);
                }
        } else {
#pragma unroll
            for (int m = 0; m < 4; ++m) {
                ushort4 o;
                o.x = f2bf(acc[m][0]); o.y = f2bf(acc[m][1]);
                o.z = f2bf(acc[m][2]); o.w = f2bf(acc[m][3]);
                *reinterpret_cast<ushort4*>(&vt_lds[m * 16 + c][wave * 16 + 4 * g]) = o;
            }
        }
    }
    __syncthreads();

    {
        const int e = t >> 2, ch = t & 3;
        bf16x8 v0 = *reinterpret_cast<const bf16x8*>(&vt_lds[e][ch * 16]);
        bf16x8 v1 = *reinterpret_cast<const bf16x8*>(&vt_lds[e][ch * 16 + 8]);
        unsigned short* vp = v_ws + ((size_t)bh * DH_ + e) * S_ + s0 + ch * 16;
        *reinterpret_cast<bf16x8*>(vp) = v0;
        *reinterpret_cast<bf16x8*>(vp + 8) = v1;
    }
}

// ---------------------------------------------------------------------------
// Attention: 8 waves x 32 q-rows (QBLK=256, 512 threads), KV tiles of 128
// (4 ks-slices/tile), plain double-buffered LDS (r7-proven skeleton), one
// barrier per tile -> 16 rounds. Swapped QK^T -> in-register P.
// ---------------------------------------------------------------------------
__global__ __launch_bounds__(512, 4) void attn_kernel(
    const unsigned short* __restrict__ q_ws, const unsigned short* __restrict__ k_ws,
    const unsigned short* __restrict__ v_ws, float* __restrict__ out)
{
    __shared__ unsigned short K_lds[2][KVBLK * 64];   // [token row][dim]
    __shared__ unsigned short V_lds[2][64 * KVBLK];   // [dim][token]

    const int nwg = gridDim.x;                         // 512, %8 == 0
    const int w   = (blockIdx.x & 7) * (nwg >> 3) + (blockIdx.x >> 3);
    const int qt  = w & 7;                             // 8 q-tiles per (b,h)
    const int bh  = w >> 3;

    const int t = threadIdx.x;                         // 0..511
    const int lane = t & 63, c = lane & 15, g = lane >> 4;
    const int wave = t >> 6;                           // 0..7
    const int qrow0 = qt * QBLK + wave * 32;

    const unsigned short* qbase = q_ws + (size_t)bh * S_ * DH_;
    const unsigned short* kbase = k_ws + (size_t)bh * S_ * DH_;
    const unsigned short* vbase = v_ws + (size_t)bh * DH_ * S_;

    // Q fragments (B-operand of swapped QK^T): [qi][kd]
    bf16x8 qa[2][2];
#pragma unroll
    for (int qi = 0; qi < 2; ++qi)
#pragma unroll
        for (int kd = 0; kd < 2; ++kd)
            qa[qi][kd] = *reinterpret_cast<const bf16x8*>(
                qbase + (size_t)(qrow0 + qi * 16 + c) * DH_ + kd * 32 + g * 8);

    // staging: K tile 128x8 chunks, V tile 64x16 chunks; 2 b128 each per thread
    const int krow = t >> 2, kch = (t & 3) * 2;   // K: rows 0..127, chunks 0..7
    const int vrow = t >> 3, vch = (t & 7) * 2;   // V: rows 0..63,  chunks 0..15
    bf16x8 kr0, kr1, vr0, vr1;
    auto load_tile = [&](int kt) {
        const unsigned short* kp = kbase + (size_t)(kt * KVBLK + krow) * DH_ + kch * 8;
        kr0 = *reinterpret_cast<const bf16x8*>(kp);
        kr1 = *reinterpret_cast<const bf16x8*>(kp + 8);
        const unsigned short* vp = vbase + (size_t)vrow * S_ + kt * KVBLK + vch * 8;
        vr0 = *reinterpret_cast<const bf16x8*>(vp);
        vr1 = *reinterpret_cast<const bf16x8*>(vp + 8);
    };
    auto store_tile = [&](int buf) {
        *reinterpret_cast<bf16x8*>(&K_lds[buf][swzK(krow, kch)])     = kr0;
        *reinterpret_cast<bf16x8*>(&K_lds[buf][swzK(krow, kch + 1)]) = kr1;
        *reinterpret_cast<bf16x8*>(&V_lds[buf][swzV(vrow, vch)])     = vr0;
        *reinterpret_cast<bf16x8*>(&V_lds[buf][swzV(vrow, vch + 1)]) = vr1;
    };

    load_tile(0);
    store_tile(0);
    __syncthreads();

    f32x4 o[2][4];
    float l[2] = {0.f, 0.f};
#pragma unroll
    for (int qi = 0; qi < 2; ++qi)
#pragma unroll
        for (int m = 0; m < 4; ++m) o[qi][m] = (f32x4){0.f, 0.f, 0.f, 0.f};

    for (int kt = 0; kt < NT; ++kt) {
        const int cur = kt & 1;
        const bool more = (kt + 1 < NT);
        if (more) load_tile(kt + 1);

        const unsigned short* Kb = &K_lds[cur][0];
        const unsigned short* Vb = &V_lds[cur][0];

        __builtin_amdgcn_s_setprio(1);
#pragma unroll
        for (int ks = 0; ks < 4; ++ks) {
            // ---- S^T = K·Q^T for this 32-k slice (2 sub-tiles nn) ----
            f32x4 s[2][2];   // [qi][nn]
#pragma unroll
            for (int nn = 0; nn < 2; ++nn) {
                const int krw = ks * 32 + nn * 16 + c;
                bf16x8 a0 = *reinterpret_cast<const bf16x8*>(&Kb[swzK(krw, g)]);
                bf16x8 a1 = *reinterpret_cast<const bf16x8*>(&Kb[swzK(krw, 4 + g)]);
#pragma unroll
                for (int qi = 0; qi < 2; ++qi) {
                    f32x4 acc = (f32x4){0.f, 0.f, 0.f, 0.f};
                    acc = __builtin_amdgcn_mfma_f32_16x16x32_bf16(a0, qa[qi][0], acc, 0, 0, 0);
                    acc = __builtin_amdgcn_mfma_f32_16x16x32_bf16(a1, qa[qi][1], acc, 0, 0, 0);
                    s[qi][nn] = acc;
                }
            }

            // ---- exp2 -> bf16 A-fragment (in-register, packing matches) ----
            bf16x8 pa[2];
#pragma unroll
            for (int qi = 0; qi < 2; ++qi) {
                float p0 = fast_exp2(s[qi][0][0]), p1 = fast_exp2(s[qi][0][1]);
                float p2 = fast_exp2(s[qi][0][2]), p3 = fast_exp2(s[qi][0][3]);
                float p4 = fast_exp2(s[qi][1][0]), p5 = fast_exp2(s[qi][1][1]);
                float p6 = fast_exp2(s[qi][1][2]), p7 = fast_exp2(s[qi][1][3]);
                l[qi] += ((p0 + p1) + (p2 + p3)) + ((p4 + p5) + (p6 + p7));
                union { unsigned int u[4]; bf16x8 v; } pk;
                pk.u[0] = cvt_pk_bf16(p0, p1);
                pk.u[1] = cvt_pk_bf16(p2, p3);
                pk.u[2] = cvt_pk_bf16(p4, p5);
                pk.u[3] = cvt_pk_bf16(p6, p7);
                pa[qi] = pk.v;
            }

            // ---- PV for this 32-k slice (each vb read feeds 2 MFMAs) ----
#pragma unroll
            for (int m = 0; m < 4; ++m) {
                bf16x8 vb = *reinterpret_cast<const bf16x8*>(&Vb[swzV(m * 16 + c, ks * 4 + g)]);
                o[0][m] = __builtin_amdgcn_mfma_f32_16x16x32_bf16(pa[0], vb, o[0][m], 0, 0, 0);
                o[1][m] = __builtin_amdgcn_mfma_f32_16x16x32_bf16(pa[1], vb, o[1][m], 0, 0, 0);
            }
        }
        __builtin_amdgcn_s_setprio(0);

        if (more) store_tile(cur ^ 1);
        __syncthreads();
    }

    // denominator: lane holds partial for q=c; reduce over the 4 g-groups
    float rl[2];
#pragma unroll
    for (int qi = 0; qi < 2; ++qi) {
        float v = l[qi];
        v += __shfl_xor(v, 16);
        v += __shfl_xor(v, 32);
        rl[qi] = v;   // all lanes: total for q = c
    }

    const int bb = bh >> 4, hh = bh & 15;
#pragma unroll
    for (int qi = 0; qi < 2; ++qi)
#pragma unroll
        for (int j = 0; j < 4; ++j) {
            // o rows are q = 4g+j; fetch l[q=4g+j] from lane (c = 4g+j, g=0)
            float inv = 1.0f / __shfl(rl[qi], 4 * g + j);
            const int srw = qrow0 + qi * 16 + 4 * g + j;
            float* op = out + (size_t)(bb * S_ + srw) * D_ + hh * DH_;
#pragma unroll
            for (int m = 0; m < 4; ++m)
                op[m * 16 + c] = o[qi][m][j] * inv;
        }
}

// ---------------------------------------------------------------------------
extern "C" void kernel_launch(void* const* d_in, const int* in_sizes, int n_in,
                              void* d_out, int out_size, void* d_ws, size_t ws_size,
                              hipStream_t stream) {
    const float* x    = (const float*)d_in[0];
    const float* Wq   = (const float*)d_in[1];
    const float* bq   = (const float*)d_in[2];
    const float* Wk   = (const float*)d_in[3];
    const float* bk   = (const float*)d_in[4];
    const float* Wv   = (const float*)d_in[5];
    const float* bv   = (const float*)d_in[6];
    const float* temp = (const float*)d_in[7];
    float* out = (float*)d_out;

    const size_t QKV_ELEMS = (size_t)B_ * H_ * S_ * DH_;   // 8388608
    unsigned short* q_ws = (unsigned short*)d_ws;
    unsigned short* k_ws = q_ws + QKV_ELEMS;
    unsigned short* v_ws = k_ws + QKV_ELEMS;

    unsigned short* wbf = (unsigned short*)d_out;   // parked; attn overwrites d_out

    wcast_kernel<<<192, 256, 0, stream>>>(Wq, Wk, Wv, wbf);

    dim3 gp(B_ * S_ / 64, H_);
    proj_kernel<<<gp, 256, 0, stream>>>(x, wbf, bq, bk, bv, temp, q_ws, k_ws, v_ws);

    dim3 ga(B_ * H_ * (S_ / QBLK));   // 512 blocks, 512 threads = 2 blocks/CU
    attn_kernel<<<ga, 512, 0, stream>>>(q_ws, k_ws, v_ws, out);
}

// Round 11
// 105.456 us; speedup vs baseline: 1.0614x; 1.0614x over previous
//
#include <hip/hip_runtime.h>
#include <hip/hip_bf16.h>

#define B_ 4
#define S_ 2048
#define D_ 1024
#define H_ 16
#define DH_ 64
#define QBLK 256
#define KVBLK 64
#define NT (S_ / KVBLK)
#define EPS_ 1e-12f
#define LOG2E_ 1.44269504f

typedef __attribute__((ext_vector_type(8))) short bf16x8;
typedef __attribute__((ext_vector_type(4))) float f32x4;

static __device__ __forceinline__ unsigned short f2bf(float f) {
    __hip_bfloat16 h = __float2bfloat16(f);
    return *reinterpret_cast<unsigned short*>(&h);
}

static __device__ __forceinline__ float fast_exp2(float x) {
#if __has_builtin(__builtin_amdgcn_exp2f)
    return __builtin_amdgcn_exp2f(x);
#else
    return exp2f(x);
#endif
}

// pack two f32 -> one u32 of 2 bf16 (lo in low half), RNE
static __device__ __forceinline__ unsigned int cvt_pk_bf16(float lo, float hi) {
    unsigned int r;
    asm("v_cvt_pk_bf16_f32 %0, %1, %2" : "=v"(r) : "v"(lo), "v"(hi));
    return r;
}

// swizzled chunk index: tiles are [row][64] ushort = 8 chunks of 16B per row.
static __device__ __forceinline__ int swz(int row, int chunk) {
    return (row << 6) + ((chunk ^ (row & 7)) << 3);
}

// k-row permutation (within 32-row blocks): label kk -> storage row, so that
// swapped-QK^T C-registers come out in PV A-fragment packing order.
// perm(8g+4nn+j) = 16nn+4g+j
static __device__ __forceinline__ int kperm(int kk) {
    return ((kk & 4) << 2) | ((kk >> 1) & 12) | (kk & 3);
}

// ---------------------------------------------------------------------------
__global__ __launch_bounds__(256) void wcast_kernel(
    const float* __restrict__ Wq, const float* __restrict__ Wk,
    const float* __restrict__ Wv, unsigned short* __restrict__ wbf)
{
    const int idx = blockIdx.x * 256 + threadIdx.x;
    const int i = idx * 4;
    const int mat = i >> 16;
    const int off = i & 65535;
    const float* src = (mat == 0) ? Wq : (mat == 1) ? Wk : Wv;
    float4 v = *reinterpret_cast<const float4*>(src + off);
    ushort4 o;
    o.x = f2bf(v.x); o.y = f2bf(v.y); o.z = f2bf(v.z); o.w = f2bf(v.w);
    *reinterpret_cast<ushort4*>(wbf + i) = o;
}

// ---------------------------------------------------------------------------
// MFMA projection (round-3 version, measured-good). Stores NORMALIZED q,k
// (q pre-scaled by temp*log2e), v^T. k rows PERMUTED (kperm) within 32-token
// blocks. q/k via direct global stores; v via LDS transpose.
// ---------------------------------------------------------------------------
__global__ __launch_bounds__(256) void proj_kernel(
    const float* __restrict__ x, const unsigned short* __restrict__ wbf,
    const float* __restrict__ bq, const float* __restrict__ bk,
    const float* __restrict__ bv, const float* __restrict__ temp,
    unsigned short* __restrict__ q_ws, unsigned short* __restrict__ k_ws,
    unsigned short* __restrict__ v_ws)
{
    __shared__ unsigned short x_lds[64][72];
    __shared__ unsigned short vt_lds[64][72];

    const int h    = blockIdx.y;
    const int tok0 = blockIdx.x * 64;
    const int b    = tok0 >> 11;
    const int s0   = tok0 & (S_ - 1);
    const int bh   = b * H_ + h;
    const int t    = threadIdx.x;
    const int wave = t >> 6, lane = t & 63, c = lane & 15, g = lane >> 4;

    {
        const int row = t >> 2, seg = t & 3;
        const float* xp = x + (size_t)(tok0 + row) * D_ + h * DH_ + seg * 16;
#pragma unroll
        for (int i = 0; i < 4; ++i) {
            float4 v = *reinterpret_cast<const float4*>(xp + i * 4);
            ushort4 o;
            o.x = f2bf(v.x); o.y = f2bf(v.y); o.z = f2bf(v.z); o.w = f2bf(v.w);
            *reinterpret_cast<ushort4*>(&x_lds[row][seg * 16 + i * 4]) = o;
        }
    }
    __syncthreads();

    bf16x8 a0 = *reinterpret_cast<const bf16x8*>(&x_lds[wave * 16 + c][g * 8]);
    bf16x8 a1 = *reinterpret_cast<const bf16x8*>(&x_lds[wave * 16 + c][32 + g * 8]);

    const float scaleq = fmaxf(temp[h], 0.01f) * LOG2E_;

#pragma unroll
    for (int mat = 0; mat < 3; ++mat) {
        const unsigned short* wb = wbf + mat * (H_ * DH_ * DH_) + h * (DH_ * DH_);
        const float* bias = ((mat == 0) ? bq : (mat == 1) ? bk : bv) + h * DH_;

        f32x4 acc[4];
#pragma unroll
        for (int m = 0; m < 4; ++m) acc[m] = (f32x4){0.f, 0.f, 0.f, 0.f};
#pragma unroll
        for (int m = 0; m < 4; ++m) {
            bf16x8 b0 = *reinterpret_cast<const bf16x8*>(wb + (m * 16 + c) * DH_ + g * 8);
            bf16x8 b1 = *reinterpret_cast<const bf16x8*>(wb + (m * 16 + c) * DH_ + 32 + g * 8);
            acc[m] = __builtin_amdgcn_mfma_f32_16x16x32_bf16(a0, b0, acc[m], 0, 0, 0);
            acc[m] = __builtin_amdgcn_mfma_f32_16x16x32_bf16(a1, b1, acc[m], 0, 0, 0);
        }
#pragma unroll
        for (int m = 0; m < 4; ++m) {
            float bm = bias[m * 16 + c];
#pragma unroll
            for (int j = 0; j < 4; ++j) acc[m][j] += bm;
        }

        if (mat < 2) {
            float rinv[4];
            const float sc = (mat == 0) ? scaleq : 1.0f;
#pragma unroll
            for (int j = 0; j < 4; ++j) {
                float p = acc[0][j] * acc[0][j] + acc[1][j] * acc[1][j] +
                          acc[2][j] * acc[2][j] + acc[3][j] * acc[3][j];
                p += __shfl_xor(p, 1); p += __shfl_xor(p, 2);
                p += __shfl_xor(p, 4); p += __shfl_xor(p, 8);
                rinv[j] = sc / fmaxf(sqrtf(p), EPS_);
            }
            unsigned short* dst = (mat == 0) ? q_ws : k_ws;
#pragma unroll
            for (int m = 0; m < 4; ++m)
#pragma unroll
                for (int j = 0; j < 4; ++j) {
                    int sl = wave * 16 + 4 * g + j;              // token within 64-tile
                    int row = (mat == 1) ? ((sl & ~31) | kperm(sl & 31)) : sl;
                    dst[((size_t)bh * S_ + s0 + row) * DH_ + m * 16 + c] =
                        f2bf(acc[m][j] * rinv[j]);
                }
        } else {
#pragma unroll
            for (int m = 0; m < 4; ++m) {
                ushort4 o;
                o.x = f2bf(acc[m][0]); o.y = f2bf(acc[m][1]);
                o.z = f2bf(acc[m][2]); o.w = f2bf(acc[m][3]);
                *reinterpret_cast<ushort4*>(&vt_lds[m * 16 + c][wave * 16 + 4 * g]) = o;
            }
        }
    }
    __syncthreads();

    {
        const int e = t >> 2, ch = t & 3;
        bf16x8 v0 = *reinterpret_cast<const bf16x8*>(&vt_lds[e][ch * 16]);
        bf16x8 v1 = *reinterpret_cast<const bf16x8*>(&vt_lds[e][ch * 16 + 8]);
        unsigned short* vp = v_ws + ((size_t)bh * DH_ + e) * S_ + s0 + ch * 16;
        *reinterpret_cast<bf16x8*>(vp) = v0;
        *reinterpret_cast<bf16x8*>(vp + 8) = v1;
    }
}

// ---------------------------------------------------------------------------
// Attention: 4 waves x 64 q-rows (QBLK=256, 256 threads), KV tiles of 64,
// double-buffered swizzled LDS (r5/r7-proven skeleton), swapped QK^T ->
// in-register P. Each K/V LDS fragment feeds 4 MFMAs (reads/MFMA = 0.25).
// Grid 512 = 2 blocks/CU (independent barriers), 8 waves/CU.
// ---------------------------------------------------------------------------
__global__ __launch_bounds__(256, 2) void attn_kernel(
    const unsigned short* __restrict__ q_ws, const unsigned short* __restrict__ k_ws,
    const unsigned short* __restrict__ v_ws, float* __restrict__ out)
{
    __shared__ unsigned short K_lds[2][64 * 64];
    __shared__ unsigned short V_lds[2][64 * 64];

    const int nwg = gridDim.x;                         // 512, %8 == 0
    const int w   = (blockIdx.x & 7) * (nwg >> 3) + (blockIdx.x >> 3);
    const int qt  = w & 7;                             // 8 q-tiles per (b,h)
    const int bh  = w >> 3;

    const int t = threadIdx.x;                         // 0..255
    const int lane = t & 63, c = lane & 15, g = lane >> 4;
    const int wave = t >> 6;                           // 0..3
    const int qrow0 = qt * QBLK + wave * 64;           // 64 q-rows per wave

    const unsigned short* qbase = q_ws + (size_t)bh * S_ * DH_;
    const unsigned short* kbase = k_ws + (size_t)bh * S_ * DH_;
    const unsigned short* vbase = v_ws + (size_t)bh * DH_ * S_;

    // Q fragments (B-operand of swapped QK^T): [qi][kd]
    bf16x8 qa[4][2];
#pragma unroll
    for (int qi = 0; qi < 4; ++qi)
#pragma unroll
        for (int kd = 0; kd < 2; ++kd)
            qa[qi][kd] = *reinterpret_cast<const bf16x8*>(
                qbase + (size_t)(qrow0 + qi * 16 + c) * DH_ + kd * 32 + g * 8);

    // staging: 256 threads cover 64 rows x 8 chunks with 2 consecutive 16B each
    const int srow = t >> 2, sch = (t & 3) * 2;
    bf16x8 kr0, kr1, vr0, vr1;
    auto load_tile = [&](int kt) {
        const unsigned short* kp = kbase + (size_t)(kt * KVBLK + srow) * DH_ + sch * 8;
        kr0 = *reinterpret_cast<const bf16x8*>(kp);
        kr1 = *reinterpret_cast<const bf16x8*>(kp + 8);
        const unsigned short* vp = vbase + (size_t)srow * S_ + kt * KVBLK + sch * 8;
        vr0 = *reinterpret_cast<const bf16x8*>(vp);
        vr1 = *reinterpret_cast<const bf16x8*>(vp + 8);
    };
    auto store_tile = [&](int buf) {
        *reinterpret_cast<bf16x8*>(&K_lds[buf][swz(srow, sch)])     = kr0;
        *reinterpret_cast<bf16x8*>(&K_lds[buf][swz(srow, sch + 1)]) = kr1;
        *reinterpret_cast<bf16x8*>(&V_lds[buf][swz(srow, sch)])     = vr0;
        *reinterpret_cast<bf16x8*>(&V_lds[buf][swz(srow, sch + 1)]) = vr1;
    };

    load_tile(0);
    store_tile(0);
    __syncthreads();

    f32x4 o[4][4];
    float l[4] = {0.f, 0.f, 0.f, 0.f};
#pragma unroll
    for (int qi = 0; qi < 4; ++qi)
#pragma unroll
        for (int m = 0; m < 4; ++m) o[qi][m] = (f32x4){0.f, 0.f, 0.f, 0.f};

    for (int kt = 0; kt < NT; ++kt) {
        const int cur = kt & 1;
        const bool more = (kt + 1 < NT);
        if (more) load_tile(kt + 1);

        const unsigned short* Kb = &K_lds[cur][0];
        const unsigned short* Vb = &V_lds[cur][0];

        __builtin_amdgcn_s_setprio(1);
#pragma unroll
        for (int ks = 0; ks < 2; ++ks) {
            // ---- S^T = K·Q^T for this 32-k slice (2 sub-tiles nn, 4 qi) ----
            f32x4 s[4][2];   // [qi][nn]
#pragma unroll
            for (int nn = 0; nn < 2; ++nn) {
                const int krow = ks * 32 + nn * 16 + c;
                bf16x8 a0 = *reinterpret_cast<const bf16x8*>(&Kb[swz(krow, g)]);
                bf16x8 a1 = *reinterpret_cast<const bf16x8*>(&Kb[swz(krow, 4 + g)]);
#pragma unroll
                for (int qi = 0; qi < 4; ++qi) {
                    f32x4 acc = (f32x4){0.f, 0.f, 0.f, 0.f};
                    acc = __builtin_amdgcn_mfma_f32_16x16x32_bf16(a0, qa[qi][0], acc, 0, 0, 0);
                    acc = __builtin_amdgcn_mfma_f32_16x16x32_bf16(a1, qa[qi][1], acc, 0, 0, 0);
                    s[qi][nn] = acc;
                }
            }

            // ---- exp2 -> bf16 A-fragment (in-register, packing matches) ----
            bf16x8 pa[4];
#pragma unroll
            for (int qi = 0; qi < 4; ++qi) {
                float p0 = fast_exp2(s[qi][0][0]), p1 = fast_exp2(s[qi][0][1]);
                float p2 = fast_exp2(s[qi][0][2]), p3 = fast_exp2(s[qi][0][3]);
                float p4 = fast_exp2(s[qi][1][0]), p5 = fast_exp2(s[qi][1][1]);
                float p6 = fast_exp2(s[qi][1][2]), p7 = fast_exp2(s[qi][1][3]);
                l[qi] += ((p0 + p1) + (p2 + p3)) + ((p4 + p5) + (p6 + p7));
                union { unsigned int u[4]; bf16x8 v; } pk;
                pk.u[0] = cvt_pk_bf16(p0, p1);
                pk.u[1] = cvt_pk_bf16(p2, p3);
                pk.u[2] = cvt_pk_bf16(p4, p5);
                pk.u[3] = cvt_pk_bf16(p6, p7);
                pa[qi] = pk.v;
            }

            // ---- PV for this 32-k slice (each vb read feeds 4 MFMAs) ----
#pragma unroll
            for (int m = 0; m < 4; ++m) {
                bf16x8 vb = *reinterpret_cast<const bf16x8*>(&Vb[swz(m * 16 + c, ks * 4 + g)]);
#pragma unroll
                for (int qi = 0; qi < 4; ++qi)
                    o[qi][m] = __builtin_amdgcn_mfma_f32_16x16x32_bf16(pa[qi], vb, o[qi][m], 0, 0, 0);
            }
        }
        __builtin_amdgcn_s_setprio(0);

        if (more) store_tile(cur ^ 1);
        __syncthreads();
    }

    // denominator: lane holds partial for q=c; reduce over the 4 g-groups
    float rl[4];
#pragma unroll
    for (int qi = 0; qi < 4; ++qi) {
        float v = l[qi];
        v += __shfl_xor(v, 16);
        v += __shfl_xor(v, 32);
        rl[qi] = v;   // all lanes: total for q = c
    }

    const int bb = bh >> 4, hh = bh & 15;
#pragma unroll
    for (int qi = 0; qi < 4; ++qi)
#pragma unroll
        for (int j = 0; j < 4; ++j) {
            // o rows are q = 4g+j; fetch l[q=4g+j] from lane (c = 4g+j, g=0)
            float inv = 1.0f / __shfl(rl[qi], 4 * g + j);
            const int srw = qrow0 + qi * 16 + 4 * g + j;
            float* op = out + (size_t)(bb * S_ + srw) * D_ + hh * DH_;
#pragma unroll
            for (int m = 0; m < 4; ++m)
                op[m * 16 + c] = o[qi][m][j] * inv;
        }
}

// ---------------------------------------------------------------------------
extern "C" void kernel_launch(void* const* d_in, const int* in_sizes, int n_in,
                              void* d_out, int out_size, void* d_ws, size_t ws_size,
                              hipStream_t stream) {
    const float* x    = (const float*)d_in[0];
    const float* Wq   = (const float*)d_in[1];
    const float* bq   = (const float*)d_in[2];
    const float* Wk   = (const float*)d_in[3];
    const float* bk   = (const float*)d_in[4];
    const float* Wv   = (const float*)d_in[5];
    const float* bv   = (const float*)d_in[6];
    const float* temp = (const float*)d_in[7];
    float* out = (float*)d_out;

    const size_t QKV_ELEMS = (size_t)B_ * H_ * S_ * DH_;   // 8388608
    unsigned short* q_ws = (unsigned short*)d_ws;
    unsigned short* k_ws = q_ws + QKV_ELEMS;
    unsigned short* v_ws = k_ws + QKV_ELEMS;

    unsigned short* wbf = (unsigned short*)d_out;   // parked; attn overwrites d_out

    wcast_kernel<<<192, 256, 0, stream>>>(Wq, Wk, Wv, wbf);

    dim3 gp(B_ * S_ / 64, H_);
    proj_kernel<<<gp, 256, 0, stream>>>(x, wbf, bq, bk, bv, temp, q_ws, k_ws, v_ws);

    dim3 ga(B_ * H_ * (S_ / QBLK));   // 512 blocks, 256 threads = 2 blocks/CU
    attn_kernel<<<ga, 256, 0, stream>>>(q_ws, k_ws, v_ws, out);
}